// Round 7
// baseline (178.911 us; speedup 1.0000x reference)
//
#include <hip/hip_runtime.h>
#include <math.h>

typedef float f32x4 __attribute__((ext_vector_type(4)));
typedef __bf16 bf16x8 __attribute__((ext_vector_type(8)));
typedef unsigned short u16x8 __attribute__((ext_vector_type(8)));

__device__ __forceinline__ unsigned short f2bf(float f) {
  unsigned u = __float_as_uint(f);
  unsigned r = (u + 0x7fffu + ((u >> 16) & 1u)) >> 16;
  return (unsigned short)r;
}
__device__ __forceinline__ float bf2f(unsigned short h) {
  return __uint_as_float(((unsigned)h) << 16);
}

// ---------------- block reduction helper ----------------
__device__ __forceinline__ float blk_sum(float v, float* red, int tid) {
  #pragma unroll
  for (int o = 32; o; o >>= 1) v += __shfl_down(v, o);
  __syncthreads();
  if ((tid & 63) == 0) red[tid >> 6] = v;
  __syncthreads();
  return red[0] + red[1] + red[2] + red[3];
}

// ---------------- softmax(freq_w) + s = irfft(softmax) + Parseval weights ----------------
__global__ __launch_bounds__(256) void k_s(const float* __restrict__ fw,
                                           float* __restrict__ s,
                                           float* __restrict__ pw) {
  __shared__ float wsh[513];
  __shared__ float red[4];
  int tid = threadIdx.x;
  float m = -1e30f;
  for (int i = tid; i < 513; i += 256) m = fmaxf(m, fw[i]);
  #pragma unroll
  for (int o = 32; o; o >>= 1) m = fmaxf(m, __shfl_down(m, o));
  if ((tid & 63) == 0) red[tid >> 6] = m;
  __syncthreads();
  m = fmaxf(fmaxf(red[0], red[1]), fmaxf(red[2], red[3]));
  float sum = 0.f;
  for (int i = tid; i < 513; i += 256) {
    float e = expf(fw[i] - m);
    wsh[i] = e;
    sum += e;
  }
  sum = blk_sum(sum, red, tid);   // syncs inside -> wsh visible after
  float inv = 1.f / sum;

  // Parseval weights: pw[f] = c_f * wnorm_f^2 / 1024, c = 1,2,...,2,1
  if (blockIdx.x == 0) {
    for (int i = tid; i < 513; i += 256) {
      float wn = wsh[i] * inv;
      float cf = (i == 0 || i == 512) ? 1.f : 2.f;
      pw[i] = cf * wn * wn * (1.f / 1024.f);
    }
  }

  int gid = blockIdx.x * 256 + tid;   // 8192 threads: d = gid>>3, chunk = gid&7
  int d = gid >> 3;
  int chunk = gid & 7;
  float acc = 0.f;
  for (int f = 1 + chunk; f < 512; f += 8) {
    int p = (f * d) & 1023;
    acc += wsh[f] * __cosf(6.283185307179586f * (float)p * (1.f / 1024.f));
  }
  acc += __shfl_xor(acc, 1);
  acc += __shfl_xor(acc, 2);
  acc += __shfl_xor(acc, 4);
  if (chunk == 0) {
    float tot = wsh[0] + ((d & 1) ? -wsh[512] : wsh[512]) + 2.f * acc;
    s[d] = tot * inv * (1.f / 1024.f);
  }
}

// ---------------- prep: cvt x, cvt proj_w, cvt down_w, fill circulant Sb ----------------
// grid 11264: [0,8192) cvt x; [8192,9216) pw; [9216,10240) dw; [10240,11264) Sb
__global__ __launch_bounds__(256) void k_prep(const float* __restrict__ x,
                                              const float* __restrict__ pw,
                                              const float* __restrict__ dw,
                                              const float* __restrict__ s,
                                              unsigned short* __restrict__ xb,
                                              unsigned short* __restrict__ pwb,
                                              unsigned short* __restrict__ dwb,
                                              unsigned short* __restrict__ Sb) {
  int b = blockIdx.x;
  int tid = threadIdx.x;
  if (b < 8192) {
    int i = b * 256 + tid;
    float4 v = ((const float4*)x)[i];
    ushort4 o;
    o.x = f2bf(v.x); o.y = f2bf(v.y); o.z = f2bf(v.z); o.w = f2bf(v.w);
    ((ushort4*)xb)[i] = o;
  } else if (b < 9216) {
    int i = (b - 8192) * 256 + tid;
    float4 v = ((const float4*)pw)[i];
    ushort4 o;
    o.x = f2bf(v.x); o.y = f2bf(v.y); o.z = f2bf(v.z); o.w = f2bf(v.w);
    ((ushort4*)pwb)[i] = o;
  } else if (b < 10240) {
    int i = (b - 9216) * 256 + tid;
    float4 v = ((const float4*)dw)[i];
    ushort4 o;
    o.x = f2bf(v.x); o.y = f2bf(v.y); o.z = f2bf(v.z); o.w = f2bf(v.w);
    ((ushort4*)dwb)[i] = o;
  } else {
    int idx = (b - 10240) * 256 + tid;    // 262144 ushort4's
    int n = idx >> 8;
    int k0 = (idx & 255) * 4;
    ushort4 o;
    o.x = f2bf(s[(k0 + 0 - n) & 1023]);
    o.y = f2bf(s[(k0 + 1 - n) & 1023]);
    o.z = f2bf(s[(k0 + 2 - n) & 1023]);
    o.w = f2bf(s[(k0 + 3 - n) & 1023]);
    ((ushort4*)Sb)[idx] = o;
  }
}

// ============ counted-vmcnt double-buffered GEMM plumbing ============
#define GB_BARRIER asm volatile("s_barrier" ::: "memory")
#define GB_WAITV(N) asm volatile("s_waitcnt vmcnt(" #N ")" ::: "memory")

// ---------------- GEMM1 128x128 tiles (512, XCD-swizzled) + W2 64x64 tiles (256, tail) ----------
__global__ __launch_bounds__(256, 2) void k_gemm1w2(const unsigned short* __restrict__ xb,
                                                    const unsigned short* __restrict__ pwb,
                                                    const unsigned short* __restrict__ dwb,
                                                    const unsigned short* __restrict__ Sb,
                                                    unsigned short* __restrict__ comp,
                                                    unsigned short* __restrict__ W2) {
  __shared__ __align__(16) unsigned short As[2][128 * 64];   // 32 KB
  __shared__ __align__(16) unsigned short Bs[2][128 * 64];   // 32 KB
  const int tid = threadIdx.x;
  const int lane = tid & 63;
  const int wave = tid >> 6;
  const int mrow = lane & 15;
  const int kq = lane >> 4;
  const int sw = mrow & 7;
  const int ar = tid >> 3;
  const int ac = (((tid & 7) ^ (ar & 7))) * 8;

  if (blockIdx.x < 512) {
    // ---- GEMM1: comp = silu(xb @ pwb^T), 128x128 tile ----
    const int xcd = blockIdx.x & 7;
    const int j = blockIdx.x >> 3;          // 0..63
    const int ntile = j & 7;                // 8 n-tiles of 128 share one A-tile per xcd
    const int bmIdx = xcd + 8 * (j >> 3);   // 0..63
    const int bm = bmIdx * 128;
    const int bn = ntile * 128;
    const int mhalf = (wave & 1) * 64;
    const int nhalf = (wave >> 1) * 64;
    f32x4 acc[4][4] = {};
    const unsigned short* Abase = xb + (size_t)(bm + ar) * 1024 + ac;
    const unsigned short* Bbase = pwb + (size_t)(bn + ar) * 1024 + ac;

#define G1_STAGE(KT, BUF)                                                                     \
    { const int k0_ = (KT) * 64;                                                              \
      _Pragma("unroll")                                                                       \
      for (int r = 0; r < 4; ++r) {                                                           \
        __builtin_amdgcn_global_load_lds(                                                     \
            (const __attribute__((address_space(1))) void*)(Abase + (size_t)(r * 32) * 1024 + k0_), \
            (__attribute__((address_space(3))) void*)((char*)As[BUF] + r * 4096 + wave * 1024), 16, 0, 0); \
        __builtin_amdgcn_global_load_lds(                                                     \
            (const __attribute__((address_space(1))) void*)(Bbase + (size_t)(r * 32) * 1024 + k0_), \
            (__attribute__((address_space(3))) void*)((char*)Bs[BUF] + r * 4096 + wave * 1024), 16, 0, 0); } }

#define G1_COMP(BUF)                                                                          \
    { const char* AsB = (const char*)As[BUF];                                                 \
      const char* BsB = (const char*)Bs[BUF];                                                 \
      _Pragma("unroll")                                                                       \
      for (int kc = 0; kc < 2; ++kc) {                                                        \
        const int chunk = (kc << 2) | kq;                                                     \
        bf16x8 af[4], bfr[4];                                                                 \
        _Pragma("unroll")                                                                     \
        for (int mt = 0; mt < 4; ++mt)                                                        \
          af[mt] = *(const bf16x8*)(AsB + (mhalf + mt * 16 + mrow) * 128 + ((chunk ^ sw) << 4)); \
        _Pragma("unroll")                                                                     \
        for (int nt = 0; nt < 4; ++nt)                                                        \
          bfr[nt] = *(const bf16x8*)(BsB + (nhalf + nt * 16 + mrow) * 128 + ((chunk ^ sw) << 4)); \
        _Pragma("unroll")                                                                     \
        for (int mt = 0; mt < 4; ++mt)                                                        \
          _Pragma("unroll")                                                                   \
          for (int nt = 0; nt < 4; ++nt)                                                      \
            acc[mt][nt] = __builtin_amdgcn_mfma_f32_16x16x32_bf16(af[mt], bfr[nt], acc[mt][nt], 0, 0, 0); } }

    G1_STAGE(0, 0);
    #pragma unroll 1
    for (int kt = 0; kt < 14; kt += 2) {
      G1_STAGE(kt + 1, 1); GB_WAITV(8); GB_BARRIER; G1_COMP(0); GB_BARRIER;
      G1_STAGE(kt + 2, 0); GB_WAITV(8); GB_BARRIER; G1_COMP(1); GB_BARRIER;
    }
    G1_STAGE(15, 1); GB_WAITV(8); GB_BARRIER; G1_COMP(0); GB_BARRIER;
    GB_WAITV(0); GB_BARRIER; G1_COMP(1);

    const int col = bn + nhalf + (lane & 15);
    const int rbase = bm + mhalf + (lane >> 4) * 4;
    #pragma unroll
    for (int mt = 0; mt < 4; ++mt)
      #pragma unroll
      for (int r = 0; r < 4; ++r) {
        const int row = rbase + mt * 16 + r;
        #pragma unroll
        for (int nt = 0; nt < 4; ++nt) {
          float v = acc[mt][nt][r];
          comp[(size_t)row * 1024 + (col + nt * 16)] = f2bf(v / (1.f + expf(-v)));
        }
      }
    return;
  }

  // ---- W2 = dwb @ Sb^T, 64x64 tile ----
  const int wbid = blockIdx.x - 512;      // 0..255
  const int bm = (wbid >> 4) * 64;
  const int bn = (wbid & 15) * 64;
  const int wm = wave & 1;
  const int wn = wave >> 1;
  f32x4 acc[2][2] = {};
  const unsigned short* Abase = dwb + (size_t)(bm + ar) * 1024 + ac;
  const unsigned short* Bbase = Sb + (size_t)(bn + ar) * 1024 + ac;

#define W2_STAGE(KT, BUF)                                                                     \
  { const int k0_ = (KT) * 64;                                                                \
    _Pragma("unroll")                                                                         \
    for (int r = 0; r < 2; ++r) {                                                             \
      __builtin_amdgcn_global_load_lds(                                                       \
          (const __attribute__((address_space(1))) void*)(Abase + (size_t)(r * 32) * 1024 + k0_), \
          (__attribute__((address_space(3))) void*)((char*)As[BUF] + r * 4096 + wave * 1024), 16, 0, 0); \
      __builtin_amdgcn_global_load_lds(                                                       \
          (const __attribute__((address_space(1))) void*)(Bbase + (size_t)(r * 32) * 1024 + k0_), \
          (__attribute__((address_space(3))) void*)((char*)Bs[BUF] + r * 4096 + wave * 1024), 16, 0, 0); } }

#define W2_COMP(BUF)                                                                          \
  { const char* AsB = (const char*)As[BUF];                                                   \
    const char* BsB = (const char*)Bs[BUF];                                                   \
    _Pragma("unroll")                                                                         \
    for (int kc = 0; kc < 2; ++kc) {                                                          \
      const int chunk = (kc << 2) | kq;                                                       \
      bf16x8 af[2], bfr[2];                                                                   \
      _Pragma("unroll")                                                                       \
      for (int mt = 0; mt < 2; ++mt)                                                          \
        af[mt] = *(const bf16x8*)(AsB + (wm * 32 + mt * 16 + mrow) * 128 + ((chunk ^ sw) << 4)); \
      _Pragma("unroll")                                                                       \
      for (int nt = 0; nt < 2; ++nt)                                                          \
        bfr[nt] = *(const bf16x8*)(BsB + (wn * 32 + nt * 16 + mrow) * 128 + ((chunk ^ sw) << 4)); \
      _Pragma("unroll")                                                                       \
      for (int mt = 0; mt < 2; ++mt)                                                          \
        _Pragma("unroll")                                                                     \
        for (int nt = 0; nt < 2; ++nt)                                                        \
          acc[mt][nt] = __builtin_amdgcn_mfma_f32_16x16x32_bf16(af[mt], bfr[nt], acc[mt][nt], 0, 0, 0); } }

  W2_STAGE(0, 0);
  #pragma unroll 1
  for (int kt = 0; kt < 14; kt += 2) {
    W2_STAGE(kt + 1, 1); GB_WAITV(4); GB_BARRIER; W2_COMP(0); GB_BARRIER;
    W2_STAGE(kt + 2, 0); GB_WAITV(4); GB_BARRIER; W2_COMP(1); GB_BARRIER;
  }
  W2_STAGE(15, 1); GB_WAITV(4); GB_BARRIER; W2_COMP(0); GB_BARRIER;
  GB_WAITV(0); GB_BARRIER; W2_COMP(1);

  const int col = bn + wn * 32 + (lane & 15);
  const int rbase = bm + wm * 32 + (lane >> 4) * 4;
  #pragma unroll
  for (int mt = 0; mt < 2; ++mt)
    #pragma unroll
    for (int nt = 0; nt < 2; ++nt)
      #pragma unroll
      for (int r = 0; r < 4; ++r) {
        int row = rbase + mt * 16 + r;
        W2[(size_t)row * 1024 + (col + nt * 16)] = f2bf(acc[mt][nt][r]);
      }
}

// ---------------- k_ln2: pure per-row LayerNorm in place (bf16 -> bf16) ----------------
__global__ __launch_bounds__(256) void k_ln2(unsigned short* __restrict__ comp,
                                             const float* __restrict__ ln_g,
                                             const float* __restrict__ ln_b) {
  __shared__ float red[4];
  const int tid = threadIdx.x;
  const size_t rowoff = (size_t)blockIdx.x * 1024;
  ushort4 cv = ((const ushort4*)(comp + rowoff))[tid];
  float x0 = bf2f(cv.x), x1 = bf2f(cv.y), x2 = bf2f(cv.z), x3 = bf2f(cv.w);
  float mu = blk_sum(x0 + x1 + x2 + x3, red, tid) * (1.f / 1024.f);
  float d0 = x0 - mu, d1 = x1 - mu, d2 = x2 - mu, d3 = x3 - mu;
  float var = blk_sum(d0 * d0 + d1 * d1 + d2 * d2 + d3 * d3, red, tid) * (1.f / 1024.f);
  float inv = rsqrtf(var + 1e-5f);
  float4 g = ((const float4*)ln_g)[tid];
  float4 b = ((const float4*)ln_b)[tid];
  ushort4 o;
  o.x = f2bf(d0 * inv * g.x + b.x);
  o.y = f2bf(d1 * inv * g.y + b.y);
  o.z = f2bf(d2 * inv * g.z + b.z);
  o.w = f2bf(d3 * inv * g.w + b.w);
  ((ushort4*)(comp + rowoff))[tid] = o;
}

// ---------------- k_fft: Parseval u2 via register FFT (1 wave/row, batched shfls) -------------
// u2[row] = sum_f pw[f]*|rfft(y)_f|^2 on the LN'd bf16 row. 512-pt complex DIT FFT in registers:
// position p=r*64+lane holds x[brev9(p)]; brev9(r*64+lane)=brev6(lane)*8+brev3(r) -> each lane
// loads a contiguous 16-elem chunk. Stages 1-6: shfl_xor with ALL 16 bpermutes batched per stage
// and sign-folded twiddles; stages 7-9 in-register. Natural-order out; conj-symmetric unpack.
#define BFLY(I, J, C, S)                                       \
  {                                                            \
    float tr_ = zr[J] * (C) - zi[J] * (S);                     \
    float ti_ = zr[J] * (S) + zi[J] * (C);                     \
    zr[J] = zr[I] - tr_; zi[J] = zi[I] - ti_;                  \
    zr[I] += tr_;        zi[I] += ti_;                         \
  }

__global__ __launch_bounds__(256) void k_fft(const unsigned short* __restrict__ comp,
                                             const float* __restrict__ pw_par,
                                             float* __restrict__ u2) {
  const int tid = threadIdx.x;
  const int lane = tid & 63;
  const int wv = tid >> 6;
  const int row = blockIdx.x * 4 + wv;
  const size_t rowoff = (size_t)row * 1024;
  const int bl = __brev((unsigned)lane) >> 26;   // brev6(lane)

  const u16x8* src = (const u16x8*)(comp + rowoff + bl * 16);
  u16x8 a0 = src[0], a1 = src[1];
  float y[16];
  #pragma unroll
  for (int i = 0; i < 8; ++i) { y[i] = bf2f(a0[i]); y[8 + i] = bf2f(a1[i]); }

  // pack: position p=r*64+lane holds z = (y[2c], y[2c+1]), c=brev3(r)
  float zr[8], zi[8];
  const int cmap[8] = {0, 4, 2, 6, 1, 5, 3, 7};   // brev3
  #pragma unroll
  for (int r = 0; r < 8; ++r) { zr[r] = y[2 * cmap[r]]; zi[r] = y[2 * cmap[r] + 1]; }

  // stages s=1..6: partner = lane ^ 2^(s-1); batched bpermutes + sign-folded twiddle.
  // low lane: u + w*v ; high lane: u - w*v  (u = low's value, v = high's value)
  #pragma unroll
  for (int s = 1; s <= 6; ++s) {
    const int half = 1 << (s - 1);
    const int pos = lane & (half - 1);
    const float ang = -3.14159265358979f * (float)pos / (float)half;
    const float c = __cosf(ang), sn = __sinf(ang);
    const bool hi = (lane & half) != 0;
    const float cs = hi ? -c : c;
    const float ss = hi ? -sn : sn;
    float pr[8], pi[8];
    #pragma unroll
    for (int r = 0; r < 8; ++r) { pr[r] = __shfl_xor(zr[r], half); pi[r] = __shfl_xor(zi[r], half); }
    #pragma unroll
    for (int r = 0; r < 8; ++r) {
      const float br = hi ? pr[r] : zr[r];
      const float bi = hi ? pi[r] : zi[r];
      const float vr = hi ? zr[r] : pr[r];
      const float vi = hi ? zi[r] : pi[r];
      zr[r] = br + cs * vr - ss * vi;
      zi[r] = bi + cs * vi + ss * vr;
    }
  }
  // stage s=7 (half=64): pairs (r, r^1), pos = lane
  {
    const float ang = -3.14159265358979f * (float)lane * (1.f / 64.f);
    const float c = __cosf(ang), sn = __sinf(ang);
    BFLY(0, 1, c, sn); BFLY(2, 3, c, sn); BFLY(4, 5, c, sn); BFLY(6, 7, c, sn);
  }
  // stage s=8 (half=128): pairs (r, r^2), pos = (r&1)*64 + lane
  {
    const float a1_ = -3.14159265358979f * (float)lane * (1.f / 128.f);
    const float a2_ = -3.14159265358979f * (float)(64 + lane) * (1.f / 128.f);
    const float ca = __cosf(a1_), sa = __sinf(a1_);
    const float cb = __cosf(a2_), sb = __sinf(a2_);
    BFLY(0, 2, ca, sa); BFLY(4, 6, ca, sa);
    BFLY(1, 3, cb, sb); BFLY(5, 7, cb, sb);
  }
  // stage s=9 (half=256): pairs (r, r^4), pos = (r&3)*64 + lane
  {
    const float a1_ = -3.14159265358979f * (float)lane * (1.f / 256.f);
    const float a2_ = -3.14159265358979f * (float)(64 + lane) * (1.f / 256.f);
    const float a3_ = -3.14159265358979f * (float)(128 + lane) * (1.f / 256.f);
    const float a4_ = -3.14159265358979f * (float)(192 + lane) * (1.f / 256.f);
    const float ca = __cosf(a1_), sa = __sinf(a1_);
    const float cb = __cosf(a2_), sb = __sinf(a2_);
    const float cc = __cosf(a3_), sc = __sinf(a3_);
    const float cd = __cosf(a4_), sd = __sinf(a4_);
    BFLY(0, 4, ca, sa); BFLY(1, 5, cb, sb); BFLY(2, 6, cc, sc); BFLY(3, 7, cd, sd);
  }

  // unpack real spectrum (Z_k at r=k>>6, lane=k&63) + Parseval; mirrors batched first.
  const int srcl = (64 - lane) & 63;
  float mrA[8], miA[8];
  #pragma unroll
  for (int r = 0; r < 8; ++r) {
    mrA[r] = __shfl(zr[7 - r], srcl);
    miA[r] = __shfl(zi[7 - r], srcl);
  }
  if (lane == 0) {
    #pragma unroll
    for (int r = 0; r < 8; ++r) { mrA[r] = zr[(8 - r) & 7]; miA[r] = zi[(8 - r) & 7]; }
  }
  float partial = 0.f;
  #pragma unroll
  for (int r = 0; r < 8; ++r) {
    const int k = r * 64 + lane;
    const float er = 0.5f * (zr[r] + mrA[r]);
    const float ei = 0.5f * (zi[r] - miA[r]);
    const float orr = 0.5f * (zi[r] + miA[r]);
    const float oi = -0.5f * (zr[r] - mrA[r]);
    const float ang = -3.14159265358979f * (float)k * (1.f / 512.f);
    const float c = __cosf(ang), sn = __sinf(ang);
    const float xr = er + orr * c - oi * sn;
    const float xi = ei + orr * sn + oi * c;
    partial += pw_par[k] * (xr * xr + xi * xi);
  }
  if (lane == 0) {
    const float x512 = zr[0] - zi[0];   // X_512 = E_0 - O_0
    partial += pw_par[512] * x512 * x512;
  }
  #pragma unroll
  for (int o = 32; o; o >>= 1) partial += __shfl_xor(partial, o);
  if (lane == 0) u2[row] = partial;
}

__device__ __forceinline__ float gamma_from_u2(float U2, float tv) {
  const float sc = 0.01f;      // sqrt(1e-4)
  const float c = 1e-4f;
  float nrm = sqrtf(U2);
  float nu = fmaxf(nrm, 1e-7f);
  float su = fminf(fmaxf(sc * nu, 1e-7f), 1.f - 1e-5f);
  float Af = tanhf((1.f - tv) * atanhf(su)) / (sc * nu);
  float nvn = fmaxf(fabsf(tv) * nrm, 1e-7f);
  float svv = fminf(fmaxf(sc * nvn, 1e-7f), 1.f - 1e-5f);
  float Bf = tv * tanhf(tv * atanhf(svv)) / (sc * nvn);
  float x2s = Af * Af * U2, y2s = Bf * Bf * U2, xys = Af * Bf * U2;
  float numc = (1.f + 2.f * c * xys + c * y2s) * Af + (1.f - c * x2s) * Bf;
  float den = fmaxf(1.f + 2.f * c * xys + c * c * x2s * y2s, 1e-7f);
  return numc / den;
}

// ---------------- GEMM3: out = gamma(u2[row]) * scale * (comp @ W2^T), fp32 out ----------------
// grid 512 (XCD-swizzled); dbuf LDS 64KB -> 2 blocks/CU.
__global__ __launch_bounds__(256, 2) void k_gemm23(const unsigned short* __restrict__ comp,
                                                   const unsigned short* __restrict__ W2,
                                                   const float* __restrict__ u2,
                                                   const float* __restrict__ t_ptr,
                                                   const float* __restrict__ scale_ptr,
                                                   float* __restrict__ out) {
  __shared__ __align__(16) unsigned short As[2][128 * 64];   // 32 KB
  __shared__ __align__(16) unsigned short Bs[2][128 * 64];   // 32 KB
  __shared__ float gs[128];
  const int tid = threadIdx.x;
  const int lane = tid & 63;
  const int wave = tid >> 6;
  const int xcd = blockIdx.x & 7;
  const int j = blockIdx.x >> 3;          // 0..63
  const int ntile = j & 7;                // 8 n-tiles of 128 share one A-tile per xcd
  const int bmIdx = xcd + 8 * (j >> 3);   // 0..63
  const int bm = bmIdx * 128;
  const int bn = ntile * 128;
  const int mrow = lane & 15;
  const int kq = lane >> 4;
  const int sw = mrow & 7;
  const int mhalf = (wave & 1) * 64;
  const int nhalf = (wave >> 1) * 64;
  const int ar = tid >> 3;
  const int ac = (((tid & 7) ^ (ar & 7))) * 8;
  const unsigned short* Abase = comp + (size_t)(bm + ar) * 1024 + ac;
  const unsigned short* Bbase = W2 + (size_t)(bn + ar) * 1024 + ac;

  // per-row gamma*scale for this block's 128 rows (u2 ready from k_fft);
  // ds_write retires with the first compute's lgkm waits; read only in epilogue.
  if (tid < 128) gs[tid] = gamma_from_u2(u2[bm + tid], t_ptr[0]) * scale_ptr[0];

  f32x4 acc[4][4] = {};

#define G3_STAGE(KT, BUF)                                                                     \
  { const int k0_ = (KT) * 64;                                                                \
    _Pragma("unroll")                                                                         \
    for (int r = 0; r < 4; ++r) {                                                             \
      __builtin_amdgcn_global_load_lds(                                                       \
          (const __attribute__((address_space(1))) void*)(Abase + (size_t)(r * 32) * 1024 + k0_), \
          (__attribute__((address_space(3))) void*)((char*)As[BUF] + r * 4096 + wave * 1024), 16, 0, 0); \
      __builtin_amdgcn_global_load_lds(                                                       \
          (const __attribute__((address_space(1))) void*)(Bbase + (size_t)(r * 32) * 1024 + k0_), \
          (__attribute__((address_space(3))) void*)((char*)Bs[BUF] + r * 4096 + wave * 1024), 16, 0, 0); } }

#define G3_COMP(BUF)                                                                          \
  { const char* AsB = (const char*)As[BUF];                                                   \
    const char* BsB = (const char*)Bs[BUF];                                                   \
    _Pragma("unroll")                                                                         \
    for (int kc = 0; kc < 2; ++kc) {                                                          \
      const int chunk = (kc << 2) | kq;                                                       \
      bf16x8 af[4], bfr[4];                                                                   \
      _Pragma("unroll")                                                                       \
      for (int mt = 0; mt < 4; ++mt)                                                          \
        af[mt] = *(const bf16x8*)(AsB + (mhalf + mt * 16 + mrow) * 128 + ((chunk ^ sw) << 4)); \
      _Pragma("unroll")                                                                       \
      for (int nt = 0; nt < 4; ++nt)                                                          \
        bfr[nt] = *(const bf16x8*)(BsB + (nhalf + nt * 16 + mrow) * 128 + ((chunk ^ sw) << 4)); \
      _Pragma("unroll")                                                                       \
      for (int mt = 0; mt < 4; ++mt)                                                          \
        _Pragma("unroll")                                                                     \
        for (int nt = 0; nt < 4; ++nt)                                                        \
          acc[mt][nt] = __builtin_amdgcn_mfma_f32_16x16x32_bf16(af[mt], bfr[nt], acc[mt][nt], 0, 0, 0); } }

  G3_STAGE(0, 0);
  #pragma unroll 1
  for (int kt = 0; kt < 14; kt += 2) {
    G3_STAGE(kt + 1, 1); GB_WAITV(8); GB_BARRIER; G3_COMP(0); GB_BARRIER;
    G3_STAGE(kt + 2, 0); GB_WAITV(8); GB_BARRIER; G3_COMP(1); GB_BARRIER;
  }
  G3_STAGE(15, 1); GB_WAITV(8); GB_BARRIER; G3_COMP(0); GB_BARRIER;
  GB_WAITV(0); GB_BARRIER; G3_COMP(1);

  const int col = bn + (wave >> 1) * 64 + (lane & 15);
  const int rbase = bm + (wave & 1) * 64 + (lane >> 4) * 4;
  #pragma unroll
  for (int mt = 0; mt < 4; ++mt)
    #pragma unroll
    for (int r = 0; r < 4; ++r) {
      const int row = rbase + mt * 16 + r;
      const float gsc = gs[row - bm];
      #pragma unroll
      for (int nt = 0; nt < 4; ++nt)
        out[(size_t)row * 1024 + (col + nt * 16)] = acc[mt][nt][r] * gsc;
    }
}

extern "C" void kernel_launch(void* const* d_in, const int* in_sizes, int n_in,
                              void* d_out, int out_size, void* d_ws, size_t ws_size,
                              hipStream_t stream) {
  const float* x      = (const float*)d_in[0];
  const float* proj_w = (const float*)d_in[1];
  const float* ln_g   = (const float*)d_in[2];
  const float* ln_b   = (const float*)d_in[3];
  const float* freq_w = (const float*)d_in[4];
  const float* t_p    = (const float*)d_in[5];
  const float* down_w = (const float*)d_in[6];
  const float* scale  = (const float*)d_in[7];

  char* ws = (char*)d_ws;
  unsigned short* xb   = (unsigned short*)ws;                 // 16 MB
  unsigned short* pwb  = (unsigned short*)(ws + (16u << 20)); // 2 MB
  unsigned short* dwb  = (unsigned short*)(ws + (18u << 20)); // 2 MB
  unsigned short* comp = (unsigned short*)(ws + (20u << 20)); // 16 MB
  unsigned short* Sb   = (unsigned short*)(ws + (36u << 20)); // 2 MB
  unsigned short* W2   = (unsigned short*)(ws + (38u << 20)); // 2 MB
  float* s_buf         = (float*)(ws + (40u << 20));          // 4 KB
  float* pw_par        = (float*)(ws + (40u << 20) + 4096);   // ~2 KB
  float* u2            = (float*)(ws + (40u << 20) + 8192);   // 32 KB

  k_s<<<32, 256, 0, stream>>>(freq_w, s_buf, pw_par);
  k_prep<<<11264, 256, 0, stream>>>(x, proj_w, down_w, s_buf, xb, pwb, dwb, Sb);
  k_gemm1w2<<<768, 256, 0, stream>>>(xb, pwb, dwb, Sb, comp, W2);
  k_ln2<<<8192, 256, 0, stream>>>(comp, ln_g, ln_b);
  k_fft<<<2048, 256, 0, stream>>>(comp, pw_par, u2);
  k_gemm23<<<512, 256, 0, stream>>>(comp, W2, u2, t_p, scale, (float*)d_out);
}

// Round 8
// 175.753 us; speedup vs baseline: 1.0180x; 1.0180x over previous
//
#include <hip/hip_runtime.h>
#include <math.h>

typedef float f32x4 __attribute__((ext_vector_type(4)));
typedef __bf16 bf16x8 __attribute__((ext_vector_type(8)));
typedef unsigned short u16x8 __attribute__((ext_vector_type(8)));

__device__ __forceinline__ unsigned short f2bf(float f) {
  unsigned u = __float_as_uint(f);
  unsigned r = (u + 0x7fffu + ((u >> 16) & 1u)) >> 16;
  return (unsigned short)r;
}
__device__ __forceinline__ float bf2f(unsigned short h) {
  return __uint_as_float(((unsigned)h) << 16);
}

// ---------------- block reduction helper ----------------
__device__ __forceinline__ float blk_sum(float v, float* red, int tid) {
  #pragma unroll
  for (int o = 32; o; o >>= 1) v += __shfl_down(v, o);
  __syncthreads();
  if ((tid & 63) == 0) red[tid >> 6] = v;
  __syncthreads();
  return red[0] + red[1] + red[2] + red[3];
}

// ---------------- softmax(freq_w) + s = irfft(softmax) + Parseval weights ----------------
__global__ __launch_bounds__(256) void k_s(const float* __restrict__ fw,
                                           float* __restrict__ s,
                                           float* __restrict__ pw) {
  __shared__ float wsh[513];
  __shared__ float red[4];
  int tid = threadIdx.x;
  float m = -1e30f;
  for (int i = tid; i < 513; i += 256) m = fmaxf(m, fw[i]);
  #pragma unroll
  for (int o = 32; o; o >>= 1) m = fmaxf(m, __shfl_down(m, o));
  if ((tid & 63) == 0) red[tid >> 6] = m;
  __syncthreads();
  m = fmaxf(fmaxf(red[0], red[1]), fmaxf(red[2], red[3]));
  float sum = 0.f;
  for (int i = tid; i < 513; i += 256) {
    float e = expf(fw[i] - m);
    wsh[i] = e;
    sum += e;
  }
  sum = blk_sum(sum, red, tid);   // syncs inside -> wsh visible after
  float inv = 1.f / sum;

  // Parseval weights: pw[f] = c_f * wnorm_f^2 / 1024, c = 1,2,...,2,1
  if (blockIdx.x == 0) {
    for (int i = tid; i < 513; i += 256) {
      float wn = wsh[i] * inv;
      float cf = (i == 0 || i == 512) ? 1.f : 2.f;
      pw[i] = cf * wn * wn * (1.f / 1024.f);
    }
  }

  int gid = blockIdx.x * 256 + tid;   // 8192 threads: d = gid>>3, chunk = gid&7
  int d = gid >> 3;
  int chunk = gid & 7;
  float acc = 0.f;
  for (int f = 1 + chunk; f < 512; f += 8) {
    int p = (f * d) & 1023;
    acc += wsh[f] * __cosf(6.283185307179586f * (float)p * (1.f / 1024.f));
  }
  acc += __shfl_xor(acc, 1);
  acc += __shfl_xor(acc, 2);
  acc += __shfl_xor(acc, 4);
  if (chunk == 0) {
    float tot = wsh[0] + ((d & 1) ? -wsh[512] : wsh[512]) + 2.f * acc;
    s[d] = tot * inv * (1.f / 1024.f);
  }
}

// ---------------- prep: cvt x, cvt proj_w, cvt down_w, fill circulant Sb ----------------
// grid 11264: [0,8192) cvt x; [8192,9216) pw; [9216,10240) dw; [10240,11264) Sb
__global__ __launch_bounds__(256) void k_prep(const float* __restrict__ x,
                                              const float* __restrict__ pw,
                                              const float* __restrict__ dw,
                                              const float* __restrict__ s,
                                              unsigned short* __restrict__ xb,
                                              unsigned short* __restrict__ pwb,
                                              unsigned short* __restrict__ dwb,
                                              unsigned short* __restrict__ Sb) {
  int b = blockIdx.x;
  int tid = threadIdx.x;
  if (b < 8192) {
    int i = b * 256 + tid;
    float4 v = ((const float4*)x)[i];
    ushort4 o;
    o.x = f2bf(v.x); o.y = f2bf(v.y); o.z = f2bf(v.z); o.w = f2bf(v.w);
    ((ushort4*)xb)[i] = o;
  } else if (b < 9216) {
    int i = (b - 8192) * 256 + tid;
    float4 v = ((const float4*)pw)[i];
    ushort4 o;
    o.x = f2bf(v.x); o.y = f2bf(v.y); o.z = f2bf(v.z); o.w = f2bf(v.w);
    ((ushort4*)pwb)[i] = o;
  } else if (b < 10240) {
    int i = (b - 9216) * 256 + tid;
    float4 v = ((const float4*)dw)[i];
    ushort4 o;
    o.x = f2bf(v.x); o.y = f2bf(v.y); o.z = f2bf(v.z); o.w = f2bf(v.w);
    ((ushort4*)dwb)[i] = o;
  } else {
    int idx = (b - 10240) * 256 + tid;    // 262144 ushort4's
    int n = idx >> 8;
    int k0 = (idx & 255) * 4;
    ushort4 o;
    o.x = f2bf(s[(k0 + 0 - n) & 1023]);
    o.y = f2bf(s[(k0 + 1 - n) & 1023]);
    o.z = f2bf(s[(k0 + 2 - n) & 1023]);
    o.w = f2bf(s[(k0 + 3 - n) & 1023]);
    ((ushort4*)Sb)[idx] = o;
  }
}

// ============ counted-vmcnt double-buffered GEMM plumbing ============
#define GB_BARRIER asm volatile("s_barrier" ::: "memory")
#define GB_WAITV(N) asm volatile("s_waitcnt vmcnt(" #N ")" ::: "memory")

// ---------------- GEMM1 128x128 tiles (512, XCD-swizzled) + W2 64x64 tiles (256, tail) ----------
__global__ __launch_bounds__(256, 2) void k_gemm1w2(const unsigned short* __restrict__ xb,
                                                    const unsigned short* __restrict__ pwb,
                                                    const unsigned short* __restrict__ dwb,
                                                    const unsigned short* __restrict__ Sb,
                                                    unsigned short* __restrict__ comp,
                                                    unsigned short* __restrict__ W2) {
  __shared__ __align__(16) unsigned short As[2][128 * 64];   // 32 KB
  __shared__ __align__(16) unsigned short Bs[2][128 * 64];   // 32 KB
  const int tid = threadIdx.x;
  const int lane = tid & 63;
  const int wave = tid >> 6;
  const int mrow = lane & 15;
  const int kq = lane >> 4;
  const int sw = mrow & 7;
  const int ar = tid >> 3;
  const int ac = (((tid & 7) ^ (ar & 7))) * 8;

  if (blockIdx.x < 512) {
    // ---- GEMM1: comp = silu(xb @ pwb^T), 128x128 tile ----
    const int xcd = blockIdx.x & 7;
    const int j = blockIdx.x >> 3;          // 0..63
    const int ntile = j & 7;                // 8 n-tiles of 128 share one A-tile per xcd
    const int bmIdx = xcd + 8 * (j >> 3);   // 0..63
    const int bm = bmIdx * 128;
    const int bn = ntile * 128;
    const int mhalf = (wave & 1) * 64;
    const int nhalf = (wave >> 1) * 64;
    f32x4 acc[4][4] = {};
    const unsigned short* Abase = xb + (size_t)(bm + ar) * 1024 + ac;
    const unsigned short* Bbase = pwb + (size_t)(bn + ar) * 1024 + ac;

#define G1_STAGE(KT, BUF)                                                                     \
    { const int k0_ = (KT) * 64;                                                              \
      _Pragma("unroll")                                                                       \
      for (int r = 0; r < 4; ++r) {                                                           \
        __builtin_amdgcn_global_load_lds(                                                     \
            (const __attribute__((address_space(1))) void*)(Abase + (size_t)(r * 32) * 1024 + k0_), \
            (__attribute__((address_space(3))) void*)((char*)As[BUF] + r * 4096 + wave * 1024), 16, 0, 0); \
        __builtin_amdgcn_global_load_lds(                                                     \
            (const __attribute__((address_space(1))) void*)(Bbase + (size_t)(r * 32) * 1024 + k0_), \
            (__attribute__((address_space(3))) void*)((char*)Bs[BUF] + r * 4096 + wave * 1024), 16, 0, 0); } }

#define G1_COMP(BUF)                                                                          \
    { const char* AsB = (const char*)As[BUF];                                                 \
      const char* BsB = (const char*)Bs[BUF];                                                 \
      _Pragma("unroll")                                                                       \
      for (int kc = 0; kc < 2; ++kc) {                                                        \
        const int chunk = (kc << 2) | kq;                                                     \
        bf16x8 af[4], bfr[4];                                                                 \
        _Pragma("unroll")                                                                     \
        for (int mt = 0; mt < 4; ++mt)                                                        \
          af[mt] = *(const bf16x8*)(AsB + (mhalf + mt * 16 + mrow) * 128 + ((chunk ^ sw) << 4)); \
        _Pragma("unroll")                                                                     \
        for (int nt = 0; nt < 4; ++nt)                                                        \
          bfr[nt] = *(const bf16x8*)(BsB + (nhalf + nt * 16 + mrow) * 128 + ((chunk ^ sw) << 4)); \
        _Pragma("unroll")                                                                     \
        for (int mt = 0; mt < 4; ++mt)                                                        \
          _Pragma("unroll")                                                                   \
          for (int nt = 0; nt < 4; ++nt)                                                      \
            acc[mt][nt] = __builtin_amdgcn_mfma_f32_16x16x32_bf16(af[mt], bfr[nt], acc[mt][nt], 0, 0, 0); } }

    G1_STAGE(0, 0);
    #pragma unroll 1
    for (int kt = 0; kt < 14; kt += 2) {
      G1_STAGE(kt + 1, 1); GB_WAITV(8); GB_BARRIER; G1_COMP(0); GB_BARRIER;
      G1_STAGE(kt + 2, 0); GB_WAITV(8); GB_BARRIER; G1_COMP(1); GB_BARRIER;
    }
    G1_STAGE(15, 1); GB_WAITV(8); GB_BARRIER; G1_COMP(0); GB_BARRIER;
    GB_WAITV(0); GB_BARRIER; G1_COMP(1);

    const int col = bn + nhalf + (lane & 15);
    const int rbase = bm + mhalf + (lane >> 4) * 4;
    #pragma unroll
    for (int mt = 0; mt < 4; ++mt)
      #pragma unroll
      for (int r = 0; r < 4; ++r) {
        const int row = rbase + mt * 16 + r;
        #pragma unroll
        for (int nt = 0; nt < 4; ++nt) {
          float v = acc[mt][nt][r];
          comp[(size_t)row * 1024 + (col + nt * 16)] = f2bf(v / (1.f + expf(-v)));
        }
      }
    return;
  }

  // ---- W2 = dwb @ Sb^T, 64x64 tile ----
  const int wbid = blockIdx.x - 512;      // 0..255
  const int bm = (wbid >> 4) * 64;
  const int bn = (wbid & 15) * 64;
  const int wm = wave & 1;
  const int wn = wave >> 1;
  f32x4 acc[2][2] = {};
  const unsigned short* Abase = dwb + (size_t)(bm + ar) * 1024 + ac;
  const unsigned short* Bbase = Sb + (size_t)(bn + ar) * 1024 + ac;

#define W2_STAGE(KT, BUF)                                                                     \
  { const int k0_ = (KT) * 64;                                                                \
    _Pragma("unroll")                                                                         \
    for (int r = 0; r < 2; ++r) {                                                             \
      __builtin_amdgcn_global_load_lds(                                                       \
          (const __attribute__((address_space(1))) void*)(Abase + (size_t)(r * 32) * 1024 + k0_), \
          (__attribute__((address_space(3))) void*)((char*)As[BUF] + r * 4096 + wave * 1024), 16, 0, 0); \
      __builtin_amdgcn_global_load_lds(                                                       \
          (const __attribute__((address_space(1))) void*)(Bbase + (size_t)(r * 32) * 1024 + k0_), \
          (__attribute__((address_space(3))) void*)((char*)Bs[BUF] + r * 4096 + wave * 1024), 16, 0, 0); } }

#define W2_COMP(BUF)                                                                          \
  { const char* AsB = (const char*)As[BUF];                                                   \
    const char* BsB = (const char*)Bs[BUF];                                                   \
    _Pragma("unroll")                                                                         \
    for (int kc = 0; kc < 2; ++kc) {                                                          \
      const int chunk = (kc << 2) | kq;                                                       \
      bf16x8 af[2], bfr[2];                                                                   \
      _Pragma("unroll")                                                                       \
      for (int mt = 0; mt < 2; ++mt)                                                          \
        af[mt] = *(const bf16x8*)(AsB + (wm * 32 + mt * 16 + mrow) * 128 + ((chunk ^ sw) << 4)); \
      _Pragma("unroll")                                                                       \
      for (int nt = 0; nt < 2; ++nt)                                                          \
        bfr[nt] = *(const bf16x8*)(BsB + (wn * 32 + nt * 16 + mrow) * 128 + ((chunk ^ sw) << 4)); \
      _Pragma("unroll")                                                                       \
      for (int mt = 0; mt < 2; ++mt)                                                          \
        _Pragma("unroll")                                                                     \
        for (int nt = 0; nt < 2; ++nt)                                                        \
          acc[mt][nt] = __builtin_amdgcn_mfma_f32_16x16x32_bf16(af[mt], bfr[nt], acc[mt][nt], 0, 0, 0); } }

  W2_STAGE(0, 0);
  #pragma unroll 1
  for (int kt = 0; kt < 14; kt += 2) {
    W2_STAGE(kt + 1, 1); GB_WAITV(4); GB_BARRIER; W2_COMP(0); GB_BARRIER;
    W2_STAGE(kt + 2, 0); GB_WAITV(4); GB_BARRIER; W2_COMP(1); GB_BARRIER;
  }
  W2_STAGE(15, 1); GB_WAITV(4); GB_BARRIER; W2_COMP(0); GB_BARRIER;
  GB_WAITV(0); GB_BARRIER; W2_COMP(1);

  const int col = bn + wn * 32 + (lane & 15);
  const int rbase = bm + wm * 32 + (lane >> 4) * 4;
  #pragma unroll
  for (int mt = 0; mt < 2; ++mt)
    #pragma unroll
    for (int nt = 0; nt < 2; ++nt)
      #pragma unroll
      for (int r = 0; r < 4; ++r) {
        int row = rbase + mt * 16 + r;
        W2[(size_t)row * 1024 + (col + nt * 16)] = f2bf(acc[mt][nt][r]);
      }
}

// ---------------- fused LayerNorm + Parseval u2 via register FFT (1 wave/row) ----------------
// Single pass over comp: load row chunk, LN in registers (wave-shfl reductions), write bf16 back,
// then 512-pt complex DIT FFT fully in registers. Stages 1-6: ALL 16 bpermutes batched per stage
// + sign-folded twiddles (select-free butterfly); stages 7-9 in-register; batched mirror unpack.
#define BFLY(I, J, C, S)                                       \
  {                                                            \
    float tr_ = zr[J] * (C) - zi[J] * (S);                     \
    float ti_ = zr[J] * (S) + zi[J] * (C);                     \
    zr[J] = zr[I] - tr_; zi[J] = zi[I] - ti_;                  \
    zr[I] += tr_;        zi[I] += ti_;                         \
  }

__global__ __launch_bounds__(256) void k_ln(unsigned short* __restrict__ comp,
                                            const float* __restrict__ ln_g,
                                            const float* __restrict__ ln_b,
                                            const float* __restrict__ pw_par,
                                            float* __restrict__ u2) {
  const int tid = threadIdx.x;
  const int lane = tid & 63;
  const int wv = tid >> 6;
  const int row = blockIdx.x * 4 + wv;
  const size_t rowoff = (size_t)row * 1024;
  const int bl = __brev((unsigned)lane) >> 26;   // brev6(lane)
  const int ybase = bl * 16;                     // lane's contiguous 16-elem chunk

  const u16x8* src = (const u16x8*)(comp + rowoff + ybase);
  u16x8 a0 = src[0], a1 = src[1];
  float y[16];
  #pragma unroll
  for (int i = 0; i < 8; ++i) { y[i] = bf2f(a0[i]); y[8 + i] = bf2f(a1[i]); }

  // LayerNorm (two-pass, wave-shfl reductions)
  float s1 = 0.f;
  #pragma unroll
  for (int i = 0; i < 16; ++i) s1 += y[i];
  #pragma unroll
  for (int o = 32; o; o >>= 1) s1 += __shfl_xor(s1, o);
  const float mu = s1 * (1.f / 1024.f);
  float s2 = 0.f;
  #pragma unroll
  for (int i = 0; i < 16; ++i) { float d = y[i] - mu; s2 += d * d; }
  #pragma unroll
  for (int o = 32; o; o >>= 1) s2 += __shfl_xor(s2, o);
  const float inv = rsqrtf(s2 * (1.f / 1024.f) + 1e-5f);

  const float4* gp = (const float4*)(ln_g + ybase);
  const float4* bp = (const float4*)(ln_b + ybase);
  #pragma unroll
  for (int q = 0; q < 4; ++q) {
    float4 g = gp[q], b = bp[q];
    y[4 * q + 0] = (y[4 * q + 0] - mu) * inv * g.x + b.x;
    y[4 * q + 1] = (y[4 * q + 1] - mu) * inv * g.y + b.y;
    y[4 * q + 2] = (y[4 * q + 2] - mu) * inv * g.z + b.z;
    y[4 * q + 3] = (y[4 * q + 3] - mu) * inv * g.w + b.w;
  }
  u16x8 o0, o1;
  #pragma unroll
  for (int i = 0; i < 8; ++i) { o0[i] = f2bf(y[i]); o1[i] = f2bf(y[8 + i]); }
  u16x8* dst = (u16x8*)(comp + rowoff + ybase);
  dst[0] = o0; dst[1] = o1;

  // pack: position p=r*64+lane holds z = (y[2c], y[2c+1]), c=brev3(r)
  float zr[8], zi[8];
  const int cmap[8] = {0, 4, 2, 6, 1, 5, 3, 7};   // brev3
  #pragma unroll
  for (int r = 0; r < 8; ++r) { zr[r] = y[2 * cmap[r]]; zi[r] = y[2 * cmap[r] + 1]; }

  // stages s=1..6: partner = lane ^ 2^(s-1); batched bpermutes + sign-folded twiddle.
  #pragma unroll
  for (int s = 1; s <= 6; ++s) {
    const int half = 1 << (s - 1);
    const int pos = lane & (half - 1);
    const float ang = -3.14159265358979f * (float)pos / (float)half;
    const float c = __cosf(ang), sn = __sinf(ang);
    const bool hi = (lane & half) != 0;
    const float cs = hi ? -c : c;
    const float ss = hi ? -sn : sn;
    float pr[8], pi[8];
    #pragma unroll
    for (int r = 0; r < 8; ++r) { pr[r] = __shfl_xor(zr[r], half); pi[r] = __shfl_xor(zi[r], half); }
    #pragma unroll
    for (int r = 0; r < 8; ++r) {
      const float br = hi ? pr[r] : zr[r];
      const float bi = hi ? pi[r] : zi[r];
      const float vr = hi ? zr[r] : pr[r];
      const float vi = hi ? zi[r] : pi[r];
      zr[r] = br + cs * vr - ss * vi;
      zi[r] = bi + cs * vi + ss * vr;
    }
  }
  // stage s=7 (half=64): pairs (r, r^1), pos = lane
  {
    const float ang = -3.14159265358979f * (float)lane * (1.f / 64.f);
    const float c = __cosf(ang), sn = __sinf(ang);
    BFLY(0, 1, c, sn); BFLY(2, 3, c, sn); BFLY(4, 5, c, sn); BFLY(6, 7, c, sn);
  }
  // stage s=8 (half=128): pairs (r, r^2), pos = (r&1)*64 + lane
  {
    const float a1_ = -3.14159265358979f * (float)lane * (1.f / 128.f);
    const float a2_ = -3.14159265358979f * (float)(64 + lane) * (1.f / 128.f);
    const float ca = __cosf(a1_), sa = __sinf(a1_);
    const float cb = __cosf(a2_), sb = __sinf(a2_);
    BFLY(0, 2, ca, sa); BFLY(4, 6, ca, sa);
    BFLY(1, 3, cb, sb); BFLY(5, 7, cb, sb);
  }
  // stage s=9 (half=256): pairs (r, r^4), pos = (r&3)*64 + lane
  {
    const float a1_ = -3.14159265358979f * (float)lane * (1.f / 256.f);
    const float a2_ = -3.14159265358979f * (float)(64 + lane) * (1.f / 256.f);
    const float a3_ = -3.14159265358979f * (float)(128 + lane) * (1.f / 256.f);
    const float a4_ = -3.14159265358979f * (float)(192 + lane) * (1.f / 256.f);
    const float ca = __cosf(a1_), sa = __sinf(a1_);
    const float cb = __cosf(a2_), sb = __sinf(a2_);
    const float cc = __cosf(a3_), sc = __sinf(a3_);
    const float cd = __cosf(a4_), sd = __sinf(a4_);
    BFLY(0, 4, ca, sa); BFLY(1, 5, cb, sb); BFLY(2, 6, cc, sc); BFLY(3, 7, cd, sd);
  }

  // unpack real spectrum (Z_k at r=k>>6, lane=k&63) + Parseval; mirrors batched first.
  const int srcl = (64 - lane) & 63;
  float mrA[8], miA[8];
  #pragma unroll
  for (int r = 0; r < 8; ++r) {
    mrA[r] = __shfl(zr[7 - r], srcl);
    miA[r] = __shfl(zi[7 - r], srcl);
  }
  if (lane == 0) {
    #pragma unroll
    for (int r = 0; r < 8; ++r) { mrA[r] = zr[(8 - r) & 7]; miA[r] = zi[(8 - r) & 7]; }
  }
  float partial = 0.f;
  #pragma unroll
  for (int r = 0; r < 8; ++r) {
    const int k = r * 64 + lane;
    const float er = 0.5f * (zr[r] + mrA[r]);
    const float ei = 0.5f * (zi[r] - miA[r]);
    const float orr = 0.5f * (zi[r] + miA[r]);
    const float oi = -0.5f * (zr[r] - mrA[r]);
    const float ang = -3.14159265358979f * (float)k * (1.f / 512.f);
    const float c = __cosf(ang), sn = __sinf(ang);
    const float xr = er + orr * c - oi * sn;
    const float xi = ei + orr * sn + oi * c;
    partial += pw_par[k] * (xr * xr + xi * xi);
  }
  if (lane == 0) {
    const float x512 = zr[0] - zi[0];   // X_512 = E_0 - O_0
    partial += pw_par[512] * x512 * x512;
  }
  #pragma unroll
  for (int o = 32; o; o >>= 1) partial += __shfl_xor(partial, o);
  if (lane == 0) u2[row] = partial;
}

__device__ __forceinline__ float gamma_from_u2(float U2, float tv) {
  const float sc = 0.01f;      // sqrt(1e-4)
  const float c = 1e-4f;
  float nrm = sqrtf(U2);
  float nu = fmaxf(nrm, 1e-7f);
  float su = fminf(fmaxf(sc * nu, 1e-7f), 1.f - 1e-5f);
  float Af = tanhf((1.f - tv) * atanhf(su)) / (sc * nu);
  float nvn = fmaxf(fabsf(tv) * nrm, 1e-7f);
  float svv = fminf(fmaxf(sc * nvn, 1e-7f), 1.f - 1e-5f);
  float Bf = tv * tanhf(tv * atanhf(svv)) / (sc * nvn);
  float x2s = Af * Af * U2, y2s = Bf * Bf * U2, xys = Af * Bf * U2;
  float numc = (1.f + 2.f * c * xys + c * y2s) * Af + (1.f - c * x2s) * Bf;
  float den = fmaxf(1.f + 2.f * c * xys + c * c * x2s * y2s, 1e-7f);
  return numc / den;
}

// ---------------- GEMM3: out = gamma(u2[row]) * scale * (comp @ W2^T), fp32 out ----------------
// grid 512 (XCD-swizzled); dbuf LDS 64KB -> 2 blocks/CU.
__global__ __launch_bounds__(256, 2) void k_gemm23(const unsigned short* __restrict__ comp,
                                                   const unsigned short* __restrict__ W2,
                                                   const float* __restrict__ u2,
                                                   const float* __restrict__ t_ptr,
                                                   const float* __restrict__ scale_ptr,
                                                   float* __restrict__ out) {
  __shared__ __align__(16) unsigned short As[2][128 * 64];   // 32 KB
  __shared__ __align__(16) unsigned short Bs[2][128 * 64];   // 32 KB
  __shared__ float gs[128];
  const int tid = threadIdx.x;
  const int lane = tid & 63;
  const int wave = tid >> 6;
  const int xcd = blockIdx.x & 7;
  const int j = blockIdx.x >> 3;          // 0..63
  const int ntile = j & 7;                // 8 n-tiles of 128 share one A-tile per xcd
  const int bmIdx = xcd + 8 * (j >> 3);   // 0..63
  const int bm = bmIdx * 128;
  const int bn = ntile * 128;
  const int mrow = lane & 15;
  const int kq = lane >> 4;
  const int sw = mrow & 7;
  const int mhalf = (wave & 1) * 64;
  const int nhalf = (wave >> 1) * 64;
  const int ar = tid >> 3;
  const int ac = (((tid & 7) ^ (ar & 7))) * 8;
  const unsigned short* Abase = comp + (size_t)(bm + ar) * 1024 + ac;
  const unsigned short* Bbase = W2 + (size_t)(bn + ar) * 1024 + ac;

  // per-row gamma*scale for this block's 128 rows (u2 ready from k_ln);
  // ds_write retires with the first compute's lgkm waits; read only in epilogue.
  if (tid < 128) gs[tid] = gamma_from_u2(u2[bm + tid], t_ptr[0]) * scale_ptr[0];

  f32x4 acc[4][4] = {};

#define G3_STAGE(KT, BUF)                                                                     \
  { const int k0_ = (KT) * 64;                                                                \
    _Pragma("unroll")                                                                         \
    for (int r = 0; r < 4; ++r) {                                                             \
      __builtin_amdgcn_global_load_lds(                                                       \
          (const __attribute__((address_space(1))) void*)(Abase + (size_t)(r * 32) * 1024 + k0_), \
          (__attribute__((address_space(3))) void*)((char*)As[BUF] + r * 4096 + wave * 1024), 16, 0, 0); \
      __builtin_amdgcn_global_load_lds(                                                       \
          (const __attribute__((address_space(1))) void*)(Bbase + (size_t)(r * 32) * 1024 + k0_), \
          (__attribute__((address_space(3))) void*)((char*)Bs[BUF] + r * 4096 + wave * 1024), 16, 0, 0); } }

#define G3_COMP(BUF)                                                                          \
  { const char* AsB = (const char*)As[BUF];                                                   \
    const char* BsB = (const char*)Bs[BUF];                                                   \
    _Pragma("unroll")                                                                         \
    for (int kc = 0; kc < 2; ++kc) {                                                          \
      const int chunk = (kc << 2) | kq;                                                       \
      bf16x8 af[4], bfr[4];                                                                   \
      _Pragma("unroll")                                                                       \
      for (int mt = 0; mt < 4; ++mt)                                                          \
        af[mt] = *(const bf16x8*)(AsB + (mhalf + mt * 16 + mrow) * 128 + ((chunk ^ sw) << 4)); \
      _Pragma("unroll")                                                                       \
      for (int nt = 0; nt < 4; ++nt)                                                          \
        bfr[nt] = *(const bf16x8*)(BsB + (nhalf + nt * 16 + mrow) * 128 + ((chunk ^ sw) << 4)); \
      _Pragma("unroll")                                                                       \
      for (int mt = 0; mt < 4; ++mt)                                                          \
        _Pragma("unroll")                                                                     \
        for (int nt = 0; nt < 4; ++nt)                                                        \
          acc[mt][nt] = __builtin_amdgcn_mfma_f32_16x16x32_bf16(af[mt], bfr[nt], acc[mt][nt], 0, 0, 0); } }

  G3_STAGE(0, 0);
  #pragma unroll 1
  for (int kt = 0; kt < 14; kt += 2) {
    G3_STAGE(kt + 1, 1); GB_WAITV(8); GB_BARRIER; G3_COMP(0); GB_BARRIER;
    G3_STAGE(kt + 2, 0); GB_WAITV(8); GB_BARRIER; G3_COMP(1); GB_BARRIER;
  }
  G3_STAGE(15, 1); GB_WAITV(8); GB_BARRIER; G3_COMP(0); GB_BARRIER;
  GB_WAITV(0); GB_BARRIER; G3_COMP(1);

  const int col = bn + (wave >> 1) * 64 + (lane & 15);
  const int rbase = bm + (wave & 1) * 64 + (lane >> 4) * 4;
  #pragma unroll
  for (int mt = 0; mt < 4; ++mt)
    #pragma unroll
    for (int r = 0; r < 4; ++r) {
      const int row = rbase + mt * 16 + r;
      const float gsc = gs[row - bm];
      #pragma unroll
      for (int nt = 0; nt < 4; ++nt)
        out[(size_t)row * 1024 + (col + nt * 16)] = acc[mt][nt][r] * gsc;
    }
}

extern "C" void kernel_launch(void* const* d_in, const int* in_sizes, int n_in,
                              void* d_out, int out_size, void* d_ws, size_t ws_size,
                              hipStream_t stream) {
  const float* x      = (const float*)d_in[0];
  const float* proj_w = (const float*)d_in[1];
  const float* ln_g   = (const float*)d_in[2];
  const float* ln_b   = (const float*)d_in[3];
  const float* freq_w = (const float*)d_in[4];
  const float* t_p    = (const float*)d_in[5];
  const float* down_w = (const float*)d_in[6];
  const float* scale  = (const float*)d_in[7];

  char* ws = (char*)d_ws;
  unsigned short* xb   = (unsigned short*)ws;                 // 16 MB
  unsigned short* pwb  = (unsigned short*)(ws + (16u << 20)); // 2 MB
  unsigned short* dwb  = (unsigned short*)(ws + (18u << 20)); // 2 MB
  unsigned short* comp = (unsigned short*)(ws + (20u << 20)); // 16 MB
  unsigned short* Sb   = (unsigned short*)(ws + (36u << 20)); // 2 MB
  unsigned short* W2   = (unsigned short*)(ws + (38u << 20)); // 2 MB
  float* s_buf         = (float*)(ws + (40u << 20));          // 4 KB
  float* pw_par        = (float*)(ws + (40u << 20) + 4096);   // ~2 KB
  float* u2            = (float*)(ws + (40u << 20) + 8192);   // 32 KB

  k_s<<<32, 256, 0, stream>>>(freq_w, s_buf, pw_par);
  k_prep<<<11264, 256, 0, stream>>>(x, proj_w, down_w, s_buf, xb, pwb, dwb, Sb);
  k_gemm1w2<<<768, 256, 0, stream>>>(xb, pwb, dwb, Sb, comp, W2);
  k_ln<<<2048, 256, 0, stream>>>(comp, ln_g, ln_b, pw_par, u2);
  k_gemm23<<<512, 256, 0, stream>>>(comp, W2, u2, t_p, scale, (float*)d_out);
}

// Round 9
// 173.491 us; speedup vs baseline: 1.0312x; 1.0130x over previous
//
#include <hip/hip_runtime.h>
#include <math.h>

typedef float f32x4 __attribute__((ext_vector_type(4)));
typedef __bf16 bf16x8 __attribute__((ext_vector_type(8)));
typedef unsigned short u16x8 __attribute__((ext_vector_type(8)));

__device__ __forceinline__ unsigned short f2bf(float f) {
  unsigned u = __float_as_uint(f);
  unsigned r = (u + 0x7fffu + ((u >> 16) & 1u)) >> 16;
  return (unsigned short)r;
}
__device__ __forceinline__ float bf2f(unsigned short h) {
  return __uint_as_float(((unsigned)h) << 16);
}

// ---------------- block reduction helper ----------------
__device__ __forceinline__ float blk_sum(float v, float* red, int tid) {
  #pragma unroll
  for (int o = 32; o; o >>= 1) v += __shfl_down(v, o);
  __syncthreads();
  if ((tid & 63) == 0) red[tid >> 6] = v;
  __syncthreads();
  return red[0] + red[1] + red[2] + red[3];
}

// ---------------- softmax(freq_w) + s = irfft(softmax) + Parseval weights ----------------
__global__ __launch_bounds__(256) void k_s(const float* __restrict__ fw,
                                           float* __restrict__ s,
                                           float* __restrict__ pw) {
  __shared__ float wsh[513];
  __shared__ float red[4];
  int tid = threadIdx.x;
  float m = -1e30f;
  for (int i = tid; i < 513; i += 256) m = fmaxf(m, fw[i]);
  #pragma unroll
  for (int o = 32; o; o >>= 1) m = fmaxf(m, __shfl_down(m, o));
  if ((tid & 63) == 0) red[tid >> 6] = m;
  __syncthreads();
  m = fmaxf(fmaxf(red[0], red[1]), fmaxf(red[2], red[3]));
  float sum = 0.f;
  for (int i = tid; i < 513; i += 256) {
    float e = expf(fw[i] - m);
    wsh[i] = e;
    sum += e;
  }
  sum = blk_sum(sum, red, tid);   // syncs inside -> wsh visible after
  float inv = 1.f / sum;

  // Parseval weights: pw[f] = c_f * wnorm_f^2 / 1024, c = 1,2,...,2,1
  if (blockIdx.x == 0) {
    for (int i = tid; i < 513; i += 256) {
      float wn = wsh[i] * inv;
      float cf = (i == 0 || i == 512) ? 1.f : 2.f;
      pw[i] = cf * wn * wn * (1.f / 1024.f);
    }
  }

  int gid = blockIdx.x * 256 + tid;   // 8192 threads: d = gid>>3, chunk = gid&7
  int d = gid >> 3;
  int chunk = gid & 7;
  float acc = 0.f;
  for (int f = 1 + chunk; f < 512; f += 8) {
    int p = (f * d) & 1023;
    acc += wsh[f] * __cosf(6.283185307179586f * (float)p * (1.f / 1024.f));
  }
  acc += __shfl_xor(acc, 1);
  acc += __shfl_xor(acc, 2);
  acc += __shfl_xor(acc, 4);
  if (chunk == 0) {
    float tot = wsh[0] + ((d & 1) ? -wsh[512] : wsh[512]) + 2.f * acc;
    s[d] = tot * inv * (1.f / 1024.f);
  }
}

// ---------------- prep: cvt x, cvt proj_w, cvt down_w, fill circulant Sb ----------------
// grid 11264: [0,8192) cvt x; [8192,9216) pw; [9216,10240) dw; [10240,11264) Sb
__global__ __launch_bounds__(256) void k_prep(const float* __restrict__ x,
                                              const float* __restrict__ pw,
                                              const float* __restrict__ dw,
                                              const float* __restrict__ s,
                                              unsigned short* __restrict__ xb,
                                              unsigned short* __restrict__ pwb,
                                              unsigned short* __restrict__ dwb,
                                              unsigned short* __restrict__ Sb) {
  int b = blockIdx.x;
  int tid = threadIdx.x;
  if (b < 8192) {
    int i = b * 256 + tid;
    float4 v = ((const float4*)x)[i];
    ushort4 o;
    o.x = f2bf(v.x); o.y = f2bf(v.y); o.z = f2bf(v.z); o.w = f2bf(v.w);
    ((ushort4*)xb)[i] = o;
  } else if (b < 9216) {
    int i = (b - 8192) * 256 + tid;
    float4 v = ((const float4*)pw)[i];
    ushort4 o;
    o.x = f2bf(v.x); o.y = f2bf(v.y); o.z = f2bf(v.z); o.w = f2bf(v.w);
    ((ushort4*)pwb)[i] = o;
  } else if (b < 10240) {
    int i = (b - 9216) * 256 + tid;
    float4 v = ((const float4*)dw)[i];
    ushort4 o;
    o.x = f2bf(v.x); o.y = f2bf(v.y); o.z = f2bf(v.z); o.w = f2bf(v.w);
    ((ushort4*)dwb)[i] = o;
  } else {
    int idx = (b - 10240) * 256 + tid;    // 262144 ushort4's
    int n = idx >> 8;
    int k0 = (idx & 255) * 4;
    ushort4 o;
    o.x = f2bf(s[(k0 + 0 - n) & 1023]);
    o.y = f2bf(s[(k0 + 1 - n) & 1023]);
    o.z = f2bf(s[(k0 + 2 - n) & 1023]);
    o.w = f2bf(s[(k0 + 3 - n) & 1023]);
    ((ushort4*)Sb)[idx] = o;
  }
}

// ============ counted-vmcnt double-buffered GEMM plumbing ============
#define GB_BARRIER asm volatile("s_barrier" ::: "memory")
#define GB_WAITV(N) asm volatile("s_waitcnt vmcnt(" #N ")" ::: "memory")

// ---------------- GEMM1 128x128 tiles (512, XCD-swizzled) + W2 64x64 tiles (256, tail) ----------
__global__ __launch_bounds__(256, 2) void k_gemm1w2(const unsigned short* __restrict__ xb,
                                                    const unsigned short* __restrict__ pwb,
                                                    const unsigned short* __restrict__ dwb,
                                                    const unsigned short* __restrict__ Sb,
                                                    unsigned short* __restrict__ comp,
                                                    unsigned short* __restrict__ W2) {
  __shared__ __align__(16) unsigned short As[2][128 * 64];   // 32 KB
  __shared__ __align__(16) unsigned short Bs[2][128 * 64];   // 32 KB
  const int tid = threadIdx.x;
  const int lane = tid & 63;
  const int wave = tid >> 6;
  const int mrow = lane & 15;
  const int kq = lane >> 4;
  const int sw = mrow & 7;
  const int ar = tid >> 3;
  const int ac = (((tid & 7) ^ (ar & 7))) * 8;

  if (blockIdx.x < 512) {
    // ---- GEMM1: comp = silu(xb @ pwb^T), 128x128 tile ----
    const int xcd = blockIdx.x & 7;
    const int j = blockIdx.x >> 3;          // 0..63
    const int ntile = j & 7;                // 8 n-tiles of 128 share one A-tile per xcd
    const int bmIdx = xcd + 8 * (j >> 3);   // 0..63
    const int bm = bmIdx * 128;
    const int bn = ntile * 128;
    const int mhalf = (wave & 1) * 64;
    const int nhalf = (wave >> 1) * 64;
    f32x4 acc[4][4] = {};
    const unsigned short* Abase = xb + (size_t)(bm + ar) * 1024 + ac;
    const unsigned short* Bbase = pwb + (size_t)(bn + ar) * 1024 + ac;

#define G1_STAGE(KT, BUF)                                                                     \
    { const int k0_ = (KT) * 64;                                                              \
      _Pragma("unroll")                                                                       \
      for (int r = 0; r < 4; ++r) {                                                           \
        __builtin_amdgcn_global_load_lds(                                                     \
            (const __attribute__((address_space(1))) void*)(Abase + (size_t)(r * 32) * 1024 + k0_), \
            (__attribute__((address_space(3))) void*)((char*)As[BUF] + r * 4096 + wave * 1024), 16, 0, 0); \
        __builtin_amdgcn_global_load_lds(                                                     \
            (const __attribute__((address_space(1))) void*)(Bbase + (size_t)(r * 32) * 1024 + k0_), \
            (__attribute__((address_space(3))) void*)((char*)Bs[BUF] + r * 4096 + wave * 1024), 16, 0, 0); } }

#define G1_COMP(BUF)                                                                          \
    { const char* AsB = (const char*)As[BUF];                                                 \
      const char* BsB = (const char*)Bs[BUF];                                                 \
      _Pragma("unroll")                                                                       \
      for (int kc = 0; kc < 2; ++kc) {                                                        \
        const int chunk = (kc << 2) | kq;                                                     \
        bf16x8 af[4], bfr[4];                                                                 \
        _Pragma("unroll")                                                                     \
        for (int mt = 0; mt < 4; ++mt)                                                        \
          af[mt] = *(const bf16x8*)(AsB + (mhalf + mt * 16 + mrow) * 128 + ((chunk ^ sw) << 4)); \
        _Pragma("unroll")                                                                     \
        for (int nt = 0; nt < 4; ++nt)                                                        \
          bfr[nt] = *(const bf16x8*)(BsB + (nhalf + nt * 16 + mrow) * 128 + ((chunk ^ sw) << 4)); \
        _Pragma("unroll")                                                                     \
        for (int mt = 0; mt < 4; ++mt)                                                        \
          _Pragma("unroll")                                                                   \
          for (int nt = 0; nt < 4; ++nt)                                                      \
            acc[mt][nt] = __builtin_amdgcn_mfma_f32_16x16x32_bf16(af[mt], bfr[nt], acc[mt][nt], 0, 0, 0); } }

    G1_STAGE(0, 0);
    #pragma unroll 1
    for (int kt = 0; kt < 14; kt += 2) {
      G1_STAGE(kt + 1, 1); GB_WAITV(8); GB_BARRIER; G1_COMP(0); GB_BARRIER;
      G1_STAGE(kt + 2, 0); GB_WAITV(8); GB_BARRIER; G1_COMP(1); GB_BARRIER;
    }
    G1_STAGE(15, 1); GB_WAITV(8); GB_BARRIER; G1_COMP(0); GB_BARRIER;
    GB_WAITV(0); GB_BARRIER; G1_COMP(1);

    const int col = bn + nhalf + (lane & 15);
    const int rbase = bm + mhalf + (lane >> 4) * 4;
    #pragma unroll
    for (int mt = 0; mt < 4; ++mt)
      #pragma unroll
      for (int r = 0; r < 4; ++r) {
        const int row = rbase + mt * 16 + r;
        #pragma unroll
        for (int nt = 0; nt < 4; ++nt) {
          float v = acc[mt][nt][r];
          comp[(size_t)row * 1024 + (col + nt * 16)] = f2bf(v / (1.f + expf(-v)));
        }
      }
    return;
  }

  // ---- W2 = dwb @ Sb^T, 64x64 tile ----
  const int wbid = blockIdx.x - 512;      // 0..255
  const int bm = (wbid >> 4) * 64;
  const int bn = (wbid & 15) * 64;
  const int wm = wave & 1;
  const int wn = wave >> 1;
  f32x4 acc[2][2] = {};
  const unsigned short* Abase = dwb + (size_t)(bm + ar) * 1024 + ac;
  const unsigned short* Bbase = Sb + (size_t)(bn + ar) * 1024 + ac;

#define W2_STAGE(KT, BUF)                                                                     \
  { const int k0_ = (KT) * 64;                                                                \
    _Pragma("unroll")                                                                         \
    for (int r = 0; r < 2; ++r) {                                                             \
      __builtin_amdgcn_global_load_lds(                                                       \
          (const __attribute__((address_space(1))) void*)(Abase + (size_t)(r * 32) * 1024 + k0_), \
          (__attribute__((address_space(3))) void*)((char*)As[BUF] + r * 4096 + wave * 1024), 16, 0, 0); \
      __builtin_amdgcn_global_load_lds(                                                       \
          (const __attribute__((address_space(1))) void*)(Bbase + (size_t)(r * 32) * 1024 + k0_), \
          (__attribute__((address_space(3))) void*)((char*)Bs[BUF] + r * 4096 + wave * 1024), 16, 0, 0); } }

#define W2_COMP(BUF)                                                                          \
  { const char* AsB = (const char*)As[BUF];                                                   \
    const char* BsB = (const char*)Bs[BUF];                                                   \
    _Pragma("unroll")                                                                         \
    for (int kc = 0; kc < 2; ++kc) {                                                          \
      const int chunk = (kc << 2) | kq;                                                       \
      bf16x8 af[2], bfr[2];                                                                   \
      _Pragma("unroll")                                                                       \
      for (int mt = 0; mt < 2; ++mt)                                                          \
        af[mt] = *(const bf16x8*)(AsB + (wm * 32 + mt * 16 + mrow) * 128 + ((chunk ^ sw) << 4)); \
      _Pragma("unroll")                                                                       \
      for (int nt = 0; nt < 2; ++nt)                                                          \
        bfr[nt] = *(const bf16x8*)(BsB + (wn * 32 + nt * 16 + mrow) * 128 + ((chunk ^ sw) << 4)); \
      _Pragma("unroll")                                                                       \
      for (int mt = 0; mt < 2; ++mt)                                                          \
        _Pragma("unroll")                                                                     \
        for (int nt = 0; nt < 2; ++nt)                                                        \
          acc[mt][nt] = __builtin_amdgcn_mfma_f32_16x16x32_bf16(af[mt], bfr[nt], acc[mt][nt], 0, 0, 0); } }

  W2_STAGE(0, 0);
  #pragma unroll 1
  for (int kt = 0; kt < 14; kt += 2) {
    W2_STAGE(kt + 1, 1); GB_WAITV(4); GB_BARRIER; W2_COMP(0); GB_BARRIER;
    W2_STAGE(kt + 2, 0); GB_WAITV(4); GB_BARRIER; W2_COMP(1); GB_BARRIER;
  }
  W2_STAGE(15, 1); GB_WAITV(4); GB_BARRIER; W2_COMP(0); GB_BARRIER;
  GB_WAITV(0); GB_BARRIER; W2_COMP(1);

  const int col = bn + wn * 32 + (lane & 15);
  const int rbase = bm + wm * 32 + (lane >> 4) * 4;
  #pragma unroll
  for (int mt = 0; mt < 2; ++mt)
    #pragma unroll
    for (int nt = 0; nt < 2; ++nt)
      #pragma unroll
      for (int r = 0; r < 4; ++r) {
        int row = rbase + mt * 16 + r;
        W2[(size_t)row * 1024 + (col + nt * 16)] = f2bf(acc[mt][nt][r]);
      }
}

// ---------------- fused LayerNorm + Parseval u2, TWO rows per wave (ILP) ----------------
// Two independent LN+FFT chains per wave, interleaved: doubles latency hiding at same
// occupancy. Twiddles/angles and ln_g/ln_b loads shared between the rows. Per-row math
// identical to the R8-passing version.
#define BFLY2(ZR, ZI, I, J, C, S)                              \
  {                                                            \
    float tr_ = ZR[J] * (C) - ZI[J] * (S);                     \
    float ti_ = ZR[J] * (S) + ZI[J] * (C);                     \
    ZR[J] = ZR[I] - tr_; ZI[J] = ZI[I] - ti_;                  \
    ZR[I] += tr_;        ZI[I] += ti_;                         \
  }

__global__ __launch_bounds__(256) void k_ln(unsigned short* __restrict__ comp,
                                            const float* __restrict__ ln_g,
                                            const float* __restrict__ ln_b,
                                            const float* __restrict__ pw_par,
                                            float* __restrict__ u2) {
  const int tid = threadIdx.x;
  const int lane = tid & 63;
  const int wv = tid >> 6;
  const int rowA = blockIdx.x * 8 + wv * 2;      // this wave: rows rowA, rowA+1
  const int rowB = rowA + 1;
  const size_t offA = (size_t)rowA * 1024;
  const size_t offB = (size_t)rowB * 1024;
  const int bl = __brev((unsigned)lane) >> 26;   // brev6(lane)
  const int ybase = bl * 16;

  const u16x8* srcA = (const u16x8*)(comp + offA + ybase);
  const u16x8* srcB = (const u16x8*)(comp + offB + ybase);
  u16x8 a0A = srcA[0], a1A = srcA[1];
  u16x8 a0B = srcB[0], a1B = srcB[1];
  float yA[16], yB[16];
  #pragma unroll
  for (int i = 0; i < 8; ++i) {
    yA[i] = bf2f(a0A[i]); yA[8 + i] = bf2f(a1A[i]);
    yB[i] = bf2f(a0B[i]); yB[8 + i] = bf2f(a1B[i]);
  }

  // LayerNorm (two-pass, wave-shfl reductions, both rows interleaved)
  float s1A = 0.f, s1B = 0.f;
  #pragma unroll
  for (int i = 0; i < 16; ++i) { s1A += yA[i]; s1B += yB[i]; }
  #pragma unroll
  for (int o = 32; o; o >>= 1) { s1A += __shfl_xor(s1A, o); s1B += __shfl_xor(s1B, o); }
  const float muA = s1A * (1.f / 1024.f);
  const float muB = s1B * (1.f / 1024.f);
  float s2A = 0.f, s2B = 0.f;
  #pragma unroll
  for (int i = 0; i < 16; ++i) {
    float dA = yA[i] - muA; s2A += dA * dA;
    float dB = yB[i] - muB; s2B += dB * dB;
  }
  #pragma unroll
  for (int o = 32; o; o >>= 1) { s2A += __shfl_xor(s2A, o); s2B += __shfl_xor(s2B, o); }
  const float invA = rsqrtf(s2A * (1.f / 1024.f) + 1e-5f);
  const float invB = rsqrtf(s2B * (1.f / 1024.f) + 1e-5f);

  const float4* gp = (const float4*)(ln_g + ybase);
  const float4* bp = (const float4*)(ln_b + ybase);
  #pragma unroll
  for (int q = 0; q < 4; ++q) {
    float4 g = gp[q], b = bp[q];
    yA[4 * q + 0] = (yA[4 * q + 0] - muA) * invA * g.x + b.x;
    yA[4 * q + 1] = (yA[4 * q + 1] - muA) * invA * g.y + b.y;
    yA[4 * q + 2] = (yA[4 * q + 2] - muA) * invA * g.z + b.z;
    yA[4 * q + 3] = (yA[4 * q + 3] - muA) * invA * g.w + b.w;
    yB[4 * q + 0] = (yB[4 * q + 0] - muB) * invB * g.x + b.x;
    yB[4 * q + 1] = (yB[4 * q + 1] - muB) * invB * g.y + b.y;
    yB[4 * q + 2] = (yB[4 * q + 2] - muB) * invB * g.z + b.z;
    yB[4 * q + 3] = (yB[4 * q + 3] - muB) * invB * g.w + b.w;
  }
  {
    u16x8 o0A, o1A, o0B, o1B;
    #pragma unroll
    for (int i = 0; i < 8; ++i) {
      o0A[i] = f2bf(yA[i]); o1A[i] = f2bf(yA[8 + i]);
      o0B[i] = f2bf(yB[i]); o1B[i] = f2bf(yB[8 + i]);
    }
    u16x8* dstA = (u16x8*)(comp + offA + ybase);
    u16x8* dstB = (u16x8*)(comp + offB + ybase);
    dstA[0] = o0A; dstA[1] = o1A;
    dstB[0] = o0B; dstB[1] = o1B;
  }

  // pack: position p=r*64+lane holds z = (y[2c], y[2c+1]), c=brev3(r)
  float zrA[8], ziA[8], zrB[8], ziB[8];
  const int cmap[8] = {0, 4, 2, 6, 1, 5, 3, 7};   // brev3
  #pragma unroll
  for (int r = 0; r < 8; ++r) {
    zrA[r] = yA[2 * cmap[r]]; ziA[r] = yA[2 * cmap[r] + 1];
    zrB[r] = yB[2 * cmap[r]]; ziB[r] = yB[2 * cmap[r] + 1];
  }

  // stages s=1..6: partner = lane ^ 2^(s-1); both rows' shfls issued together.
  #pragma unroll
  for (int s = 1; s <= 6; ++s) {
    const int half = 1 << (s - 1);
    const int pos = lane & (half - 1);
    const float ang = -3.14159265358979f * (float)pos / (float)half;
    const float c = __cosf(ang), sn = __sinf(ang);
    const bool hi = (lane & half) != 0;
    const float cs = hi ? -c : c;
    const float ss = hi ? -sn : sn;
    float prA[8], piA[8], prB[8], piB[8];
    #pragma unroll
    for (int r = 0; r < 8; ++r) {
      prA[r] = __shfl_xor(zrA[r], half); piA[r] = __shfl_xor(ziA[r], half);
      prB[r] = __shfl_xor(zrB[r], half); piB[r] = __shfl_xor(ziB[r], half);
    }
    #pragma unroll
    for (int r = 0; r < 8; ++r) {
      {
        const float br = hi ? prA[r] : zrA[r];
        const float bi = hi ? piA[r] : ziA[r];
        const float vr = hi ? zrA[r] : prA[r];
        const float vi = hi ? ziA[r] : piA[r];
        zrA[r] = br + cs * vr - ss * vi;
        ziA[r] = bi + cs * vi + ss * vr;
      }
      {
        const float br = hi ? prB[r] : zrB[r];
        const float bi = hi ? piB[r] : ziB[r];
        const float vr = hi ? zrB[r] : prB[r];
        const float vi = hi ? ziB[r] : piB[r];
        zrB[r] = br + cs * vr - ss * vi;
        ziB[r] = bi + cs * vi + ss * vr;
      }
    }
  }
  // stage s=7 (half=64): pairs (r, r^1), pos = lane
  {
    const float ang = -3.14159265358979f * (float)lane * (1.f / 64.f);
    const float c = __cosf(ang), sn = __sinf(ang);
    BFLY2(zrA, ziA, 0, 1, c, sn); BFLY2(zrA, ziA, 2, 3, c, sn);
    BFLY2(zrA, ziA, 4, 5, c, sn); BFLY2(zrA, ziA, 6, 7, c, sn);
    BFLY2(zrB, ziB, 0, 1, c, sn); BFLY2(zrB, ziB, 2, 3, c, sn);
    BFLY2(zrB, ziB, 4, 5, c, sn); BFLY2(zrB, ziB, 6, 7, c, sn);
  }
  // stage s=8 (half=128): pairs (r, r^2), pos = (r&1)*64 + lane
  {
    const float a1_ = -3.14159265358979f * (float)lane * (1.f / 128.f);
    const float a2_ = -3.14159265358979f * (float)(64 + lane) * (1.f / 128.f);
    const float ca = __cosf(a1_), sa = __sinf(a1_);
    const float cb = __cosf(a2_), sb = __sinf(a2_);
    BFLY2(zrA, ziA, 0, 2, ca, sa); BFLY2(zrA, ziA, 4, 6, ca, sa);
    BFLY2(zrA, ziA, 1, 3, cb, sb); BFLY2(zrA, ziA, 5, 7, cb, sb);
    BFLY2(zrB, ziB, 0, 2, ca, sa); BFLY2(zrB, ziB, 4, 6, ca, sa);
    BFLY2(zrB, ziB, 1, 3, cb, sb); BFLY2(zrB, ziB, 5, 7, cb, sb);
  }
  // stage s=9 (half=256): pairs (r, r^4), pos = (r&3)*64 + lane
  {
    const float a1_ = -3.14159265358979f * (float)lane * (1.f / 256.f);
    const float a2_ = -3.14159265358979f * (float)(64 + lane) * (1.f / 256.f);
    const float a3_ = -3.14159265358979f * (float)(128 + lane) * (1.f / 256.f);
    const float a4_ = -3.14159265358979f * (float)(192 + lane) * (1.f / 256.f);
    const float ca = __cosf(a1_), sa = __sinf(a1_);
    const float cb = __cosf(a2_), sb = __sinf(a2_);
    const float cc = __cosf(a3_), sc = __sinf(a3_);
    const float cd = __cosf(a4_), sd = __sinf(a4_);
    BFLY2(zrA, ziA, 0, 4, ca, sa); BFLY2(zrA, ziA, 1, 5, cb, sb);
    BFLY2(zrA, ziA, 2, 6, cc, sc); BFLY2(zrA, ziA, 3, 7, cd, sd);
    BFLY2(zrB, ziB, 0, 4, ca, sa); BFLY2(zrB, ziB, 1, 5, cb, sb);
    BFLY2(zrB, ziB, 2, 6, cc, sc); BFLY2(zrB, ziB, 3, 7, cd, sd);
  }

  // unpack real spectrum (Z_k at r=k>>6, lane=k&63) + Parseval; both rows' mirrors batched.
  const int srcl = (64 - lane) & 63;
  float mrA[8], miA[8], mrB[8], miB[8];
  #pragma unroll
  for (int r = 0; r < 8; ++r) {
    mrA[r] = __shfl(zrA[7 - r], srcl); miA[r] = __shfl(ziA[7 - r], srcl);
    mrB[r] = __shfl(zrB[7 - r], srcl); miB[r] = __shfl(ziB[7 - r], srcl);
  }
  if (lane == 0) {
    #pragma unroll
    for (int r = 0; r < 8; ++r) {
      mrA[r] = zrA[(8 - r) & 7]; miA[r] = ziA[(8 - r) & 7];
      mrB[r] = zrB[(8 - r) & 7]; miB[r] = ziB[(8 - r) & 7];
    }
  }
  float pA = 0.f, pB = 0.f;
  #pragma unroll
  for (int r = 0; r < 8; ++r) {
    const int k = r * 64 + lane;
    const float ang = -3.14159265358979f * (float)k * (1.f / 512.f);
    const float c = __cosf(ang), sn = __sinf(ang);
    const float w = pw_par[k];
    {
      const float er = 0.5f * (zrA[r] + mrA[r]);
      const float ei = 0.5f * (ziA[r] - miA[r]);
      const float orr = 0.5f * (ziA[r] + miA[r]);
      const float oi = -0.5f * (zrA[r] - mrA[r]);
      const float xr = er + orr * c - oi * sn;
      const float xi = ei + orr * sn + oi * c;
      pA += w * (xr * xr + xi * xi);
    }
    {
      const float er = 0.5f * (zrB[r] + mrB[r]);
      const float ei = 0.5f * (ziB[r] - miB[r]);
      const float orr = 0.5f * (ziB[r] + miB[r]);
      const float oi = -0.5f * (zrB[r] - mrB[r]);
      const float xr = er + orr * c - oi * sn;
      const float xi = ei + orr * sn + oi * c;
      pB += w * (xr * xr + xi * xi);
    }
  }
  if (lane == 0) {
    const float w512 = pw_par[512];
    const float xA = zrA[0] - ziA[0];
    const float xB = zrB[0] - ziB[0];
    pA += w512 * xA * xA;
    pB += w512 * xB * xB;
  }
  #pragma unroll
  for (int o = 32; o; o >>= 1) { pA += __shfl_xor(pA, o); pB += __shfl_xor(pB, o); }
  if (lane == 0) { u2[rowA] = pA; u2[rowB] = pB; }
}

__device__ __forceinline__ float gamma_from_u2(float U2, float tv) {
  const float sc = 0.01f;      // sqrt(1e-4)
  const float c = 1e-4f;
  float nrm = sqrtf(U2);
  float nu = fmaxf(nrm, 1e-7f);
  float su = fminf(fmaxf(sc * nu, 1e-7f), 1.f - 1e-5f);
  float Af = tanhf((1.f - tv) * atanhf(su)) / (sc * nu);
  float nvn = fmaxf(fabsf(tv) * nrm, 1e-7f);
  float svv = fminf(fmaxf(sc * nvn, 1e-7f), 1.f - 1e-5f);
  float Bf = tv * tanhf(tv * atanhf(svv)) / (sc * nvn);
  float x2s = Af * Af * U2, y2s = Bf * Bf * U2, xys = Af * Bf * U2;
  float numc = (1.f + 2.f * c * xys + c * y2s) * Af + (1.f - c * x2s) * Bf;
  float den = fmaxf(1.f + 2.f * c * xys + c * c * x2s * y2s, 1e-7f);
  return numc / den;
}

// ---------------- GEMM3: out = gamma(u2[row]) * scale * (comp @ W2^T), fp32 out ----------------
// grid 512 (XCD-swizzled); dbuf LDS 64KB -> 2 blocks/CU.
__global__ __launch_bounds__(256, 2) void k_gemm23(const unsigned short* __restrict__ comp,
                                                   const unsigned short* __restrict__ W2,
                                                   const float* __restrict__ u2,
                                                   const float* __restrict__ t_ptr,
                                                   const float* __restrict__ scale_ptr,
                                                   float* __restrict__ out) {
  __shared__ __align__(16) unsigned short As[2][128 * 64];   // 32 KB
  __shared__ __align__(16) unsigned short Bs[2][128 * 64];   // 32 KB
  __shared__ float gs[128];
  const int tid = threadIdx.x;
  const int lane = tid & 63;
  const int wave = tid >> 6;
  const int xcd = blockIdx.x & 7;
  const int j = blockIdx.x >> 3;          // 0..63
  const int ntile = j & 7;                // 8 n-tiles of 128 share one A-tile per xcd
  const int bmIdx = xcd + 8 * (j >> 3);   // 0..63
  const int bm = bmIdx * 128;
  const int bn = ntile * 128;
  const int mrow = lane & 15;
  const int kq = lane >> 4;
  const int sw = mrow & 7;
  const int mhalf = (wave & 1) * 64;
  const int nhalf = (wave >> 1) * 64;
  const int ar = tid >> 3;
  const int ac = (((tid & 7) ^ (ar & 7))) * 8;
  const unsigned short* Abase = comp + (size_t)(bm + ar) * 1024 + ac;
  const unsigned short* Bbase = W2 + (size_t)(bn + ar) * 1024 + ac;

  // per-row gamma*scale for this block's 128 rows (u2 ready from k_ln);
  // ds_write retires with the first compute's lgkm waits; read only in epilogue.
  if (tid < 128) gs[tid] = gamma_from_u2(u2[bm + tid], t_ptr[0]) * scale_ptr[0];

  f32x4 acc[4][4] = {};

#define G3_STAGE(KT, BUF)                                                                     \
  { const int k0_ = (KT) * 64;                                                                \
    _Pragma("unroll")                                                                         \
    for (int r = 0; r < 4; ++r) {                                                             \
      __builtin_amdgcn_global_load_lds(                                                       \
          (const __attribute__((address_space(1))) void*)(Abase + (size_t)(r * 32) * 1024 + k0_), \
          (__attribute__((address_space(3))) void*)((char*)As[BUF] + r * 4096 + wave * 1024), 16, 0, 0); \
      __builtin_amdgcn_global_load_lds(                                                       \
          (const __attribute__((address_space(1))) void*)(Bbase + (size_t)(r * 32) * 1024 + k0_), \
          (__attribute__((address_space(3))) void*)((char*)Bs[BUF] + r * 4096 + wave * 1024), 16, 0, 0); } }

#define G3_COMP(BUF)                                                                          \
  { const char* AsB = (const char*)As[BUF];                                                   \
    const char* BsB = (const char*)Bs[BUF];                                                   \
    _Pragma("unroll")                                                                         \
    for (int kc = 0; kc < 2; ++kc) {                                                          \
      const int chunk = (kc << 2) | kq;                                                       \
      bf16x8 af[4], bfr[4];                                                                   \
      _Pragma("unroll")                                                                       \
      for (int mt = 0; mt < 4; ++mt)                                                          \
        af[mt] = *(const bf16x8*)(AsB + (mhalf + mt * 16 + mrow) * 128 + ((chunk ^ sw) << 4)); \
      _Pragma("unroll")                                                                       \
      for (int nt = 0; nt < 4; ++nt)                                                          \
        bfr[nt] = *(const bf16x8*)(BsB + (nhalf + nt * 16 + mrow) * 128 + ((chunk ^ sw) << 4)); \
      _Pragma("unroll")                                                                       \
      for (int mt = 0; mt < 4; ++mt)                                                          \
        _Pragma("unroll")                                                                     \
        for (int nt = 0; nt < 4; ++nt)                                                        \
          acc[mt][nt] = __builtin_amdgcn_mfma_f32_16x16x32_bf16(af[mt], bfr[nt], acc[mt][nt], 0, 0, 0); } }

  G3_STAGE(0, 0);
  #pragma unroll 1
  for (int kt = 0; kt < 14; kt += 2) {
    G3_STAGE(kt + 1, 1); GB_WAITV(8); GB_BARRIER; G3_COMP(0); GB_BARRIER;
    G3_STAGE(kt + 2, 0); GB_WAITV(8); GB_BARRIER; G3_COMP(1); GB_BARRIER;
  }
  G3_STAGE(15, 1); GB_WAITV(8); GB_BARRIER; G3_COMP(0); GB_BARRIER;
  GB_WAITV(0); GB_BARRIER; G3_COMP(1);

  const int col = bn + (wave >> 1) * 64 + (lane & 15);
  const int rbase = bm + (wave & 1) * 64 + (lane >> 4) * 4;
  #pragma unroll
  for (int mt = 0; mt < 4; ++mt)
    #pragma unroll
    for (int r = 0; r < 4; ++r) {
      const int row = rbase + mt * 16 + r;
      const float gsc = gs[row - bm];
      #pragma unroll
      for (int nt = 0; nt < 4; ++nt)
        out[(size_t)row * 1024 + (col + nt * 16)] = acc[mt][nt][r] * gsc;
    }
}

extern "C" void kernel_launch(void* const* d_in, const int* in_sizes, int n_in,
                              void* d_out, int out_size, void* d_ws, size_t ws_size,
                              hipStream_t stream) {
  const float* x      = (const float*)d_in[0];
  const float* proj_w = (const float*)d_in[1];
  const float* ln_g   = (const float*)d_in[2];
  const float* ln_b   = (const float*)d_in[3];
  const float* freq_w = (const float*)d_in[4];
  const float* t_p    = (const float*)d_in[5];
  const float* down_w = (const float*)d_in[6];
  const float* scale  = (const float*)d_in[7];

  char* ws = (char*)d_ws;
  unsigned short* xb   = (unsigned short*)ws;                 // 16 MB
  unsigned short* pwb  = (unsigned short*)(ws + (16u << 20)); // 2 MB
  unsigned short* dwb  = (unsigned short*)(ws + (18u << 20)); // 2 MB
  unsigned short* comp = (unsigned short*)(ws + (20u << 20)); // 16 MB
  unsigned short* Sb   = (unsigned short*)(ws + (36u << 20)); // 2 MB
  unsigned short* W2   = (unsigned short*)(ws + (38u << 20)); // 2 MB
  float* s_buf         = (float*)(ws + (40u << 20));          // 4 KB
  float* pw_par        = (float*)(ws + (40u << 20) + 4096);   // ~2 KB
  float* u2            = (float*)(ws + (40u << 20) + 8192);   // 32 KB

  k_s<<<32, 256, 0, stream>>>(freq_w, s_buf, pw_par);
  k_prep<<<11264, 256, 0, stream>>>(x, proj_w, down_w, s_buf, xb, pwb, dwb, Sb);
  k_gemm1w2<<<768, 256, 0, stream>>>(xb, pwb, dwb, Sb, comp, W2);
  k_ln<<<1024, 256, 0, stream>>>(comp, ln_g, ln_b, pw_par, u2);
  k_gemm23<<<512, 256, 0, stream>>>(comp, W2, u2, t_p, scale, (float*)d_out);
}